// Round 14
// baseline (101.132 us; speedup 1.0000x reference)
//
#include <hip/hip_runtime.h>
#include <math.h>

#define TPB 256
constexpr int Bn = 64;
constexpr int Ln = 262144;          // 2^18
constexpr int S  = 2048;            // chunk/tile size
constexpr int NC = Ln / S;          // 128 chunks per row
constexpr int HA = S + 301;         // halo'd extent (2349)
constexpr int EPT = 11;             // segment length; ODD stride -> conflict-free LDS
constexpr int OPT = S / TPB;        // 8 outputs per thread
constexpr int LDSZ = 2820;          // 1 (shift) + 11*256=2816 coverage + pad
constexpr int NW = TPB / 64;

constexpr float TWO_PI_F = 6.28318530717958647692f;
constexpr float PI_F = 3.14159265358979323846f;
constexpr float HALF_PI_F = 1.57079632679489661923f;
constexpr float INV_TWO_PI_F = 0.15915494309189533577f;

// wrap count: k = floor((d+pi)/(2pi)), with the reference's dm==-pi & d>0 fixup.
__device__ __forceinline__ int wrap_k(float d) {
    float kf = floorf(__fmaf_rn(d, INV_TWO_PI_F, 0.5f));
    float dm = __fmaf_rn(-kf, TWO_PI_F, d);
    if (dm == -PI_F && d > 0.f) kf -= 1.f;
    return (int)kf;
}

// polynomial atan2, abs err ~2e-7 rad
__device__ __forceinline__ float fast_atan2f(float q, float i) {
    float aq = fabsf(q), ai = fabsf(i);
    float mx = fmaxf(aq, ai), mn = fminf(aq, ai);
    float r = __builtin_amdgcn_rcpf(mx);
    r = r * (2.0f - mx * r);                 // one NR step
    float t = mn * r;                        // in [0, 1+eps]
    if (mx == 0.f) t = 0.f;                  // atan2(0,0) -> 0
    float s = t * t;
    float p = __fmaf_rn(s, 0.0028662257f, -0.0161657367f);
    p = __fmaf_rn(p, s,  0.0429096138f);
    p = __fmaf_rn(p, s, -0.0752896400f);
    p = __fmaf_rn(p, s,  0.1065626393f);
    p = __fmaf_rn(p, s, -0.1420889944f);
    p = __fmaf_rn(p, s,  0.1999355085f);
    p = __fmaf_rn(p, s, -0.3333314528f);
    float at = __fmaf_rn(p * s, t, t);       // t + t*s*poly
    if (aq > ai) at = HALF_PI_F - at;
    if (i < 0.f) at = PI_F - at;
    return (q < 0.f) ? -at : at;
}

// K1: locally-anchored unwrap + moving-average high-pass. Registers own the
// raw values end-to-end; LDS receives ONLY the two inclusive-prefix arrays.
// Thread t owns elements li = 11t-1 .. 11t+10 (x[0] = predecessor).
__global__ __launch_bounds__(TPB, 7) void k_filt(const float* __restrict__ Ig,
                                                 const float* __restrict__ Qg,
                                                 int* __restrict__ Ag,     // local scan at g=t0-1
                                                 int* __restrict__ Bg,     // local scan at g=t0+S-1
                                                 float* __restrict__ out,
                                                 float* __restrict__ PS) {
    __shared__ __align__(16) float spu_s[LDSZ];   // prefix(pu)
    __shared__ __align__(16) float smg_s[LDSZ];   // prefix(magnitude)
    __shared__ int iwt[NW];
    __shared__ float fwt[NW];
    __shared__ float fwt2[NW];
    __shared__ float rbuf[NW][4];
    float* spu = spu_s + 1;             // logical li -> spu[li]
    float* smg = smg_s + 1;

    const int c = blockIdx.x, b = blockIdx.y;
    const int t0 = c * S;
    const int base = t0 - 151;
    const int tid = threadIdx.x;
    const int lane = tid & 63, wid = tid >> 6;
    const bool edge = (c == 0) | (c == NC - 1);
    const float* Ib = Ig + (size_t)b * Ln;
    const float* Qb = Qg + (size_t)b * Ln;

    const int seg = tid * EPT;          // li of x[1]
    const int gs = base + seg - 1;      // g of x[0]

    // own 12 elements: load + convert, all in registers (no LDS staging)
    float ph[12], mg[12];
    if (!edge) {
        // interior: gs >= t0-152 >= 1896 and gs+11 <= t0+2664 <= Ln-1432: in range
#pragma unroll
        for (int i = 0; i < 12; ++i) {
            float a = Ib[gs + i], q = Qb[gs + i];
            ph[i] = fast_atan2f(q, a);
            mg[i] = __builtin_amdgcn_sqrtf(__fmaf_rn(a, a, q * q));
        }
    } else {
#pragma unroll
        for (int i = 0; i < 12; ++i) {
            int g = gs + i;
            float a = 0.f, q = 0.f;
            if (g >= 0 && g < Ln) { a = Ib[g]; q = Qb[g]; }
            ph[i] = fast_atan2f(q, a);   // (0,0) -> 0 like zero-pad
            mg[i] = __builtin_amdgcn_sqrtf(__fmaf_rn(a, a, q * q));
        }
    }

    // wrap scan + mg sum (registers only; no barrier needed yet)
    int kloc[12];
    kloc[0] = 0;
    float rm = 0.f;
    {
        int run = 0;
#pragma unroll
        for (int i = 1; i < 12; ++i) {
            run += wrap_k(ph[i] - ph[i - 1]);
            kloc[i] = run;
            rm += mg[i];
        }
    }

    // combined block exclusive scan: int wrap counts + float mg sums
    int vi_ = kloc[11];
    float vf = rm;
#pragma unroll
    for (int o = 1; o < 64; o <<= 1) {
        int ui = __shfl_up(vi_, o, 64);
        float uf = __shfl_up(vf, o, 64);
        if (lane >= o) { vi_ += ui; vf += uf; }
    }
    if (lane == 63) { iwt[wid] = vi_; fwt[wid] = vf; }
    __syncthreads();                                   // B2
    int addi = 0; float addf = 0.f;
#pragma unroll
    for (int w = 0; w < NW; ++w) {
        addi += (w < wid) ? iwt[w] : 0;
        addf += (w < wid) ? fwt[w] : 0.f;
    }
    const int excl = vi_ - kloc[11] + addi;
    const float em = vf - rm + addf;

    if (tid == 13)  Ag[b * NC + c] = excl + kloc[8];   // scan at li=150  (g=t0-1)
    if (tid == 199) Bg[b * NC + c] = excl + kloc[10];  // scan at li=2198 (g=t0+S-1)

    // pu segment sum from registers
    float rp = 0.f;
    if (!edge) {
#pragma unroll
        for (int i = 1; i < 12; ++i)
            rp += __fmaf_rn((float)(excl + kloc[i]), TWO_PI_F, ph[i]);
    } else {
#pragma unroll
        for (int i = 1; i < 12; ++i) {
            int g = gs + i;
            if (g >= 0 && g < Ln)
                rp += __fmaf_rn((float)(excl + kloc[i]), TWO_PI_F, ph[i]);
        }
    }

    // block exclusive scan of pu sums
    float incf = rp;
#pragma unroll
    for (int o = 1; o < 64; o <<= 1) {
        float uf = __shfl_up(incf, o, 64);
        if (lane >= o) incf += uf;
    }
    if (lane == 63) fwt2[wid] = incf;
    __syncthreads();                                   // B3
    float addp = 0.f;
#pragma unroll
    for (int w = 0; w < NW; ++w) addp += (w < wid) ? fwt2[w] : 0.f;
    const float ep = incf - rp + addp;

    // write inclusive prefixes from registers (stride-11, conflict-free,
    // write-only LDS)
    if (!edge) {
        float runp = ep, runm = em;
#pragma unroll
        for (int i = 1; i < 12; ++i) {
            int li = seg + i - 1;
            runp += __fmaf_rn((float)(excl + kloc[i]), TWO_PI_F, ph[i]);
            spu[li] = runp;
            runm += mg[i];
            smg[li] = runm;
        }
    } else {
        float runp = ep, runm = em;
#pragma unroll
        for (int i = 1; i < 12; ++i) {
            int li = seg + i - 1;
            int g = gs + i;
            float v = 0.f;
            if (g >= 0 && g < Ln)
                v = __fmaf_rn((float)(excl + kloc[i]), TWO_PI_F, ph[i]);
            runp += v;
            spu[li] = runp;
            runm += mg[i];
            smg[li] = runm;
        }
    }
    __syncthreads();                                   // B4

    float s1mf = 0.f, s2mf = 0.f, s1pf = 0.f, s2pf = 0.f;
    float* om = out + ((size_t)b * 2) * Ln + t0;
    float* op = out + ((size_t)b * 2 + 1) * Ln + t0;
    constexpr float INV_K = 1.0f / 301.0f;
#pragma unroll
    for (int j = 0; j < OPT; ++j) {
        int t = tid + j * TPB;
        int lt = t + 151;
        float Mq = smg[lt - 151], Mm = smg[lt - 1], Ml = smg[lt], Mp = smg[lt + 150];
        float Pq = spu[lt - 151], Pm = spu[lt - 1], Pl = spu[lt], Pp = spu[lt + 150];
        float fm = (Ml - Mm) - (Mp - Mq) * INV_K;
        float fp = (Pl - Pm) - (Pp - Pq) * INV_K;
        om[t] = fm;
        op[t] = fp;
        s1mf += fm; s2mf = __fmaf_rn(fm, fm, s2mf);
        s1pf += fp; s2pf = __fmaf_rn(fp, fp, s2pf);
    }
    // f32 wave reduce
#pragma unroll
    for (int o = 32; o > 0; o >>= 1) {
        s1mf += __shfl_down(s1mf, o, 64);
        s2mf += __shfl_down(s2mf, o, 64);
        s1pf += __shfl_down(s1pf, o, 64);
        s2pf += __shfl_down(s2pf, o, 64);
    }
    if (lane == 0) { rbuf[wid][0] = s1mf; rbuf[wid][1] = s2mf; rbuf[wid][2] = s1pf; rbuf[wid][3] = s2pf; }
    __syncthreads();                                   // B5
    if (tid == 0) {
        float t0f = 0.f, t1f = 0.f, t2f = 0.f, t3f = 0.f;
#pragma unroll
        for (int w = 0; w < NW; ++w) {
            t0f += rbuf[w][0]; t1f += rbuf[w][1]; t2f += rbuf[w][2]; t3f += rbuf[w][3];
        }
        float* p = PS + (size_t)(b * NC + c) * 4;
        p[0] = t0f; p[1] = t1f; p[2] = t2f; p[3] = t3f;
    }
}

// K2: per-row: fix last-150 phase outputs (right-pad windows) + row stats.
// One wave per row (NC==128: two chunks per lane).
__global__ void k_post(const int* __restrict__ Ag, const int* __restrict__ Bg,
                       float* __restrict__ out, const float* __restrict__ PS,
                       float* __restrict__ ROW) {
    const int b = blockIdx.x;
    const int lane = threadIdx.x;           // 64 threads
    const int idx = b * NC;

    // row wrap offset at chunk NC-1 start: sum W_c over c<NC-1
    int w = (Bg[idx + lane] - Ag[idx + lane]);
    if (lane + 64 < NC - 1) w += (Bg[idx + 64 + lane] - Ag[idx + 64 + lane]);
#pragma unroll
    for (int o = 32; o > 0; o >>= 1) w += __shfl_down(w, o, 64);
    int O = __shfl(w, 0, 64);
    int aL = Ag[idx + NC - 1];
    float C = TWO_PI_F * (float)(O - aL);   // pu_true - pu_prov for last chunk

    constexpr float INV_K = 1.0f / 301.0f;
    float* op = out + ((size_t)b * 2 + 1) * Ln;
    double sd = 0.0, sd2 = 0.0;
#pragma unroll
    for (int k = 0; k < 3; ++k) {
        int j = lane + k * 64;
        if (j < 150) {
            int t = Ln - 150 + j;           // npad in window = j+1
            float delta = C * (float)(j + 1) * INV_K;
            float v = op[t];
            float nv = v + delta;
            op[t] = nv;
            sd += (double)delta;
            sd2 += (double)nv * (double)nv - (double)v * (double)v;
        }
    }

    // row stats: each lane sums 2 chunks, plus its own fix deltas
    const float* p1 = PS + (size_t)(idx + lane) * 4;
    const float* p2 = PS + (size_t)(idx + 64 + lane) * 4;
    double a0 = (double)p1[0] + (double)p2[0];
    double a1 = (double)p1[1] + (double)p2[1];
    double a2 = (double)p1[2] + (double)p2[2] + sd;
    double a3 = (double)p1[3] + (double)p2[3] + sd2;
#pragma unroll
    for (int o = 32; o > 0; o >>= 1) {
        a0 += __shfl_down(a0, o, 64);
        a1 += __shfl_down(a1, o, 64);
        a2 += __shfl_down(a2, o, 64);
        a3 += __shfl_down(a3, o, 64);
    }
    if (lane == 0) {
        double Ld = (double)Ln;
        double mm = a0 / Ld;
        double vm = (a1 - a0 * a0 / Ld) / (Ld - 1.0); vm = vm > 0 ? vm : 0;
        double mp = a2 / Ld;
        double vp = (a3 - a2 * a2 / Ld) / (Ld - 1.0); vp = vp > 0 ? vp : 0;
        float* r = ROW + b * 4;
        r[0] = (float)mm;
        r[1] = (float)(1.0 / (sqrt(vm) + 1e-5));
        r[2] = (float)mp;
        r[3] = (float)(1.0 / (sqrt(vp) + 1e-5));
    }
}

// in-place normalize of d_out
__global__ __launch_bounds__(256) void k_norm(float* __restrict__ out,
                                              const float* __restrict__ ROW) {
    const size_t n4 = (size_t)Bn * 2 * Ln / 4;
    size_t stride = (size_t)gridDim.x * blockDim.x;
    for (size_t p4 = (size_t)blockIdx.x * blockDim.x + threadIdx.x; p4 < n4; p4 += stride) {
        size_t p = p4 * 4;
        int b = (int)(p >> 19);             // 2L = 2^19
        int sig = (int)((p >> 18) & 1);     // L = 2^18
        float mean = ROW[b * 4 + sig * 2];
        float scale = ROW[b * 4 + sig * 2 + 1];
        float4 v = reinterpret_cast<float4*>(out)[p4];
        v.x = (v.x - mean) * scale;
        v.y = (v.y - mean) * scale;
        v.z = (v.z - mean) * scale;
        v.w = (v.w - mean) * scale;
        reinterpret_cast<float4*>(out)[p4] = v;
    }
}

extern "C" void kernel_launch(void* const* d_in, const int* in_sizes, int n_in,
                              void* d_out, int out_size, void* d_ws, size_t ws_size,
                              hipStream_t stream) {
    const float* Ig = (const float*)d_in[0];
    const float* Qg = (const float*)d_in[1];
    float* out = (float*)d_out;
    char* ws = (char*)d_ws;
    int* Ag = (int*)ws;                                 // Bn*NC ints (32 KiB)
    int* Bg = (int*)(ws + 32768);                       // Bn*NC ints (32 KiB)
    float* PS = (float*)(ws + 65536);                   // Bn*NC*4 floats (128 KiB)
    float* ROW = (float*)(ws + 65536 + (size_t)Bn * NC * 4 * sizeof(float));

    dim3 grid(NC, Bn);
    hipLaunchKernelGGL(k_filt, grid, dim3(TPB), 0, stream, Ig, Qg, Ag, Bg, out, PS);
    hipLaunchKernelGGL(k_post, dim3(Bn), dim3(64), 0, stream, Ag, Bg, out, PS, ROW);
    hipLaunchKernelGGL(k_norm, dim3(4096), dim3(256), 0, stream, out, ROW);
}

// Round 15
// 98.805 us; speedup vs baseline: 1.0236x; 1.0236x over previous
//
#include <hip/hip_runtime.h>
#include <math.h>
#include <stdint.h>

#define TPB 256
constexpr int Bn = 64;
constexpr int Ln = 262144;          // 2^18
constexpr int S  = 2048;            // chunk/tile size
constexpr int NC = Ln / S;          // 128 chunks per row
constexpr int HA = S + 301;         // halo'd extent (2349)
constexpr int EPT = 11;             // segment length; ODD stride -> conflict-free LDS
constexpr int OPT = S / TPB;        // 8 outputs per thread
constexpr int NF4 = 641;            // float4s DMA'd per array (2564 floats, slots [0,2564))
constexpr int LDSZ = 2820;          // slots; writes reach 2816, reads 2816
constexpr int NW = TPB / 64;

constexpr float TWO_PI_F = 6.28318530717958647692f;
constexpr float PI_F = 3.14159265358979323846f;
constexpr float HALF_PI_F = 1.57079632679489661923f;
constexpr float INV_TWO_PI_F = 0.15915494309189533577f;

// wrap count: k = floor((d+pi)/(2pi)), with the reference's dm==-pi & d>0 fixup.
__device__ __forceinline__ int wrap_k(float d) {
    float kf = floorf(__fmaf_rn(d, INV_TWO_PI_F, 0.5f));
    float dm = __fmaf_rn(-kf, TWO_PI_F, d);
    if (dm == -PI_F && d > 0.f) kf -= 1.f;
    return (int)kf;
}

// polynomial atan2, abs err ~2e-7 rad
__device__ __forceinline__ float fast_atan2f(float q, float i) {
    float aq = fabsf(q), ai = fabsf(i);
    float mx = fmaxf(aq, ai), mn = fminf(aq, ai);
    float r = __builtin_amdgcn_rcpf(mx);
    r = r * (2.0f - mx * r);                 // one NR step
    float t = mn * r;                        // in [0, 1+eps]
    if (mx == 0.f) t = 0.f;                  // atan2(0,0) -> 0
    float s = t * t;
    float p = __fmaf_rn(s, 0.0028662257f, -0.0161657367f);
    p = __fmaf_rn(p, s,  0.0429096138f);
    p = __fmaf_rn(p, s, -0.0752896400f);
    p = __fmaf_rn(p, s,  0.1065626393f);
    p = __fmaf_rn(p, s, -0.1420889944f);
    p = __fmaf_rn(p, s,  0.1999355085f);
    p = __fmaf_rn(p, s, -0.3333314528f);
    float at = __fmaf_rn(p * s, t, t);       // t + t*s*poly
    if (aq > ai) at = HALF_PI_F - at;
    if (i < 0.f) at = PI_F - at;
    return (q < 0.f) ? -at : at;
}

// direct global->LDS DMA, 16 bytes per lane; lds_base must be wave-uniform
__device__ __forceinline__ void gload_lds16(const float* g, float* lds_base) {
    __builtin_amdgcn_global_load_lds(
        (__attribute__((address_space(1))) void*)(uintptr_t)(const void*)g,
        (__attribute__((address_space(3))) void*)(uintptr_t)(void*)lds_base,
        16, 0, 0);
}

// K1: locally-anchored unwrap + moving-average high-pass. DMA stages raw I/Q
// into LDS; threads convert their own stride-11 segments in registers; the
// same LDS buffers are then overwritten with the two inclusive-prefix arrays.
// Slot mapping: slot k holds element li = k-1 (raw), then prefix at li = k-1.
__global__ __launch_bounds__(TPB, 7) void k_filt(const float* __restrict__ Ig,
                                                 const float* __restrict__ Qg,
                                                 int* __restrict__ Ag,     // local scan at g=t0-1
                                                 int* __restrict__ Bg,     // local scan at g=t0+S-1
                                                 float* __restrict__ out,
                                                 float* __restrict__ PS) {
    __shared__ __align__(16) float sI_s[LDSZ];    // raw I -> prefix(pu)
    __shared__ __align__(16) float sQ_s[LDSZ];    // raw Q -> prefix(magnitude)
    __shared__ int iwt[NW];
    __shared__ float fwt[NW];
    __shared__ float fwt2[NW];
    __shared__ float rbuf[NW][4];
    float* spu = sI_s + 1;              // prefix(pu)[li]  at slot li+1
    float* smg = sQ_s + 1;              // prefix(mg)[li]  at slot li+1

    const int c = blockIdx.x, b = blockIdx.y;
    const int t0 = c * S;
    const int base = t0 - 151;
    const int astart = base - 1;        // slot 0 <-> g = astart; 16B-aligned
    const int tid = threadIdx.x;
    const int lane = tid & 63, wid = tid >> 6;
    const bool edge = (c == 0) | (c == NC - 1);
    const float* Ib = Ig + (size_t)b * Ln;
    const float* Qb = Qg + (size_t)b * Ln;

    if (!edge) {
        // interior: slots [0,2564) fully in-range -> DMA both arrays
        const float* gI = Ib + astart;
        const float* gQ = Qb + astart;
#pragma unroll
        for (int k = wid; k < 11; k += NW) {
            int f = k * 64 + lane;
            if (f < NF4) {
                gload_lds16(gI + 4 * f, sI_s + k * 256);
                gload_lds16(gQ + 4 * f, sQ_s + k * 256);
            }
        }
    } else {
        // edge chunks (c==0, c==NC-1): guarded scalar staging of raw I/Q
#pragma unroll
        for (int j = 0; j < 10; ++j) {
            int k = tid + j * TPB;      // slot
            int g = astart + k;
            float a = 0.f, q = 0.f;
            if (g >= 0 && g < Ln) { a = Ib[g]; q = Qb[g]; }
            sI_s[k] = a;
            sQ_s[k] = q;
        }
    }
    __syncthreads();                                   // B1 (DMA drained)

    const int seg = tid * EPT;          // li of x[1]
    const int kb = seg;                 // slot of x[0] (= li seg-1)
    const int gs = astart + kb;         // g of x[0]

    // convert own 12 elements from LDS raw -> registers
    float ph[12], mg[12];
#pragma unroll
    for (int i = 0; i < 12; ++i) {
        float a = sI_s[kb + i], q = sQ_s[kb + i];
        ph[i] = fast_atan2f(q, a);
        mg[i] = __builtin_amdgcn_sqrtf(__fmaf_rn(a, a, q * q));
    }

    // wrap scan + mg sum (registers only)
    int kloc[12];
    kloc[0] = 0;
    float rm = 0.f;
    {
        int run = 0;
#pragma unroll
        for (int i = 1; i < 12; ++i) {
            run += wrap_k(ph[i] - ph[i - 1]);
            kloc[i] = run;
            rm += mg[i];
        }
    }

    // combined block exclusive scan: int wrap counts + float mg sums
    int vi_ = kloc[11];
    float vf = rm;
#pragma unroll
    for (int o = 1; o < 64; o <<= 1) {
        int ui = __shfl_up(vi_, o, 64);
        float uf = __shfl_up(vf, o, 64);
        if (lane >= o) { vi_ += ui; vf += uf; }
    }
    if (lane == 63) { iwt[wid] = vi_; fwt[wid] = vf; }
    __syncthreads();                                   // B2
    int addi = 0; float addf = 0.f;
#pragma unroll
    for (int w = 0; w < NW; ++w) {
        addi += (w < wid) ? iwt[w] : 0;
        addf += (w < wid) ? fwt[w] : 0.f;
    }
    const int excl = vi_ - kloc[11] + addi;
    const float em = vf - rm + addf;

    if (tid == 13)  Ag[b * NC + c] = excl + kloc[8];   // scan at li=150  (g=t0-1)
    if (tid == 199) Bg[b * NC + c] = excl + kloc[10];  // scan at li=2198 (g=t0+S-1)

    // pu segment sum from registers
    float rp = 0.f;
    if (!edge) {
#pragma unroll
        for (int i = 1; i < 12; ++i)
            rp += __fmaf_rn((float)(excl + kloc[i]), TWO_PI_F, ph[i]);
    } else {
#pragma unroll
        for (int i = 1; i < 12; ++i) {
            int g = gs + i;
            if (g >= 0 && g < Ln)
                rp += __fmaf_rn((float)(excl + kloc[i]), TWO_PI_F, ph[i]);
        }
    }

    // block exclusive scan of pu sums
    float incf = rp;
#pragma unroll
    for (int o = 1; o < 64; o <<= 1) {
        float uf = __shfl_up(incf, o, 64);
        if (lane >= o) incf += uf;
    }
    if (lane == 63) fwt2[wid] = incf;
    __syncthreads();                                   // B3 (raw reads all done)
    float addp = 0.f;
#pragma unroll
    for (int w = 0; w < NW; ++w) addp += (w < wid) ? fwt2[w] : 0.f;
    const float ep = incf - rp + addp;

    // overwrite LDS with inclusive prefixes from registers (stride-11,
    // conflict-free, write-only)
    if (!edge) {
        float runp = ep, runm = em;
#pragma unroll
        for (int i = 1; i < 12; ++i) {
            int li = seg + i - 1;
            runp += __fmaf_rn((float)(excl + kloc[i]), TWO_PI_F, ph[i]);
            spu[li] = runp;
            runm += mg[i];
            smg[li] = runm;
        }
    } else {
        float runp = ep, runm = em;
#pragma unroll
        for (int i = 1; i < 12; ++i) {
            int li = seg + i - 1;
            int g = gs + i;
            float v = 0.f;
            if (g >= 0 && g < Ln)
                v = __fmaf_rn((float)(excl + kloc[i]), TWO_PI_F, ph[i]);
            runp += v;
            spu[li] = runp;
            runm += mg[i];
            smg[li] = runm;
        }
    }
    __syncthreads();                                   // B4

    float s1mf = 0.f, s2mf = 0.f, s1pf = 0.f, s2pf = 0.f;
    float* om = out + ((size_t)b * 2) * Ln + t0;
    float* op = out + ((size_t)b * 2 + 1) * Ln + t0;
    constexpr float INV_K = 1.0f / 301.0f;
#pragma unroll
    for (int j = 0; j < OPT; ++j) {
        int t = tid + j * TPB;
        int lt = t + 151;
        float Mq = smg[lt - 151], Mm = smg[lt - 1], Ml = smg[lt], Mp = smg[lt + 150];
        float Pq = spu[lt - 151], Pm = spu[lt - 1], Pl = spu[lt], Pp = spu[lt + 150];
        float fm = (Ml - Mm) - (Mp - Mq) * INV_K;
        float fp = (Pl - Pm) - (Pp - Pq) * INV_K;
        om[t] = fm;
        op[t] = fp;
        s1mf += fm; s2mf = __fmaf_rn(fm, fm, s2mf);
        s1pf += fp; s2pf = __fmaf_rn(fp, fp, s2pf);
    }
    // f32 wave reduce
#pragma unroll
    for (int o = 32; o > 0; o >>= 1) {
        s1mf += __shfl_down(s1mf, o, 64);
        s2mf += __shfl_down(s2mf, o, 64);
        s1pf += __shfl_down(s1pf, o, 64);
        s2pf += __shfl_down(s2pf, o, 64);
    }
    if (lane == 0) { rbuf[wid][0] = s1mf; rbuf[wid][1] = s2mf; rbuf[wid][2] = s1pf; rbuf[wid][3] = s2pf; }
    __syncthreads();                                   // B5
    if (tid == 0) {
        float t0f = 0.f, t1f = 0.f, t2f = 0.f, t3f = 0.f;
#pragma unroll
        for (int w = 0; w < NW; ++w) {
            t0f += rbuf[w][0]; t1f += rbuf[w][1]; t2f += rbuf[w][2]; t3f += rbuf[w][3];
        }
        float* p = PS + (size_t)(b * NC + c) * 4;
        p[0] = t0f; p[1] = t1f; p[2] = t2f; p[3] = t3f;
    }
}

// K2: per-row: fix last-150 phase outputs (right-pad windows) + row stats.
// One wave per row (NC==128: two chunks per lane).
__global__ void k_post(const int* __restrict__ Ag, const int* __restrict__ Bg,
                       float* __restrict__ out, const float* __restrict__ PS,
                       float* __restrict__ ROW) {
    const int b = blockIdx.x;
    const int lane = threadIdx.x;           // 64 threads
    const int idx = b * NC;

    // row wrap offset at chunk NC-1 start: sum W_c over c<NC-1
    int w = (Bg[idx + lane] - Ag[idx + lane]);
    if (lane + 64 < NC - 1) w += (Bg[idx + 64 + lane] - Ag[idx + 64 + lane]);
#pragma unroll
    for (int o = 32; o > 0; o >>= 1) w += __shfl_down(w, o, 64);
    int O = __shfl(w, 0, 64);
    int aL = Ag[idx + NC - 1];
    float C = TWO_PI_F * (float)(O - aL);   // pu_true - pu_prov for last chunk

    constexpr float INV_K = 1.0f / 301.0f;
    float* op = out + ((size_t)b * 2 + 1) * Ln;
    double sd = 0.0, sd2 = 0.0;
#pragma unroll
    for (int k = 0; k < 3; ++k) {
        int j = lane + k * 64;
        if (j < 150) {
            int t = Ln - 150 + j;           // npad in window = j+1
            float delta = C * (float)(j + 1) * INV_K;
            float v = op[t];
            float nv = v + delta;
            op[t] = nv;
            sd += (double)delta;
            sd2 += (double)nv * (double)nv - (double)v * (double)v;
        }
    }

    // row stats: each lane sums 2 chunks, plus its own fix deltas
    const float* p1 = PS + (size_t)(idx + lane) * 4;
    const float* p2 = PS + (size_t)(idx + 64 + lane) * 4;
    double a0 = (double)p1[0] + (double)p2[0];
    double a1 = (double)p1[1] + (double)p2[1];
    double a2 = (double)p1[2] + (double)p2[2] + sd;
    double a3 = (double)p1[3] + (double)p2[3] + sd2;
#pragma unroll
    for (int o = 32; o > 0; o >>= 1) {
        a0 += __shfl_down(a0, o, 64);
        a1 += __shfl_down(a1, o, 64);
        a2 += __shfl_down(a2, o, 64);
        a3 += __shfl_down(a3, o, 64);
    }
    if (lane == 0) {
        double Ld = (double)Ln;
        double mm = a0 / Ld;
        double vm = (a1 - a0 * a0 / Ld) / (Ld - 1.0); vm = vm > 0 ? vm : 0;
        double mp = a2 / Ld;
        double vp = (a3 - a2 * a2 / Ld) / (Ld - 1.0); vp = vp > 0 ? vp : 0;
        float* r = ROW + b * 4;
        r[0] = (float)mm;
        r[1] = (float)(1.0 / (sqrt(vm) + 1e-5));
        r[2] = (float)mp;
        r[3] = (float)(1.0 / (sqrt(vp) + 1e-5));
    }
}

// in-place normalize of d_out
__global__ __launch_bounds__(256) void k_norm(float* __restrict__ out,
                                              const float* __restrict__ ROW) {
    const size_t n4 = (size_t)Bn * 2 * Ln / 4;
    size_t stride = (size_t)gridDim.x * blockDim.x;
    for (size_t p4 = (size_t)blockIdx.x * blockDim.x + threadIdx.x; p4 < n4; p4 += stride) {
        size_t p = p4 * 4;
        int b = (int)(p >> 19);             // 2L = 2^19
        int sig = (int)((p >> 18) & 1);     // L = 2^18
        float mean = ROW[b * 4 + sig * 2];
        float scale = ROW[b * 4 + sig * 2 + 1];
        float4 v = reinterpret_cast<float4*>(out)[p4];
        v.x = (v.x - mean) * scale;
        v.y = (v.y - mean) * scale;
        v.z = (v.z - mean) * scale;
        v.w = (v.w - mean) * scale;
        reinterpret_cast<float4*>(out)[p4] = v;
    }
}

extern "C" void kernel_launch(void* const* d_in, const int* in_sizes, int n_in,
                              void* d_out, int out_size, void* d_ws, size_t ws_size,
                              hipStream_t stream) {
    const float* Ig = (const float*)d_in[0];
    const float* Qg = (const float*)d_in[1];
    float* out = (float*)d_out;
    char* ws = (char*)d_ws;
    int* Ag = (int*)ws;                                 // Bn*NC ints (32 KiB)
    int* Bg = (int*)(ws + 32768);                       // Bn*NC ints (32 KiB)
    float* PS = (float*)(ws + 65536);                   // Bn*NC*4 floats (128 KiB)
    float* ROW = (float*)(ws + 65536 + (size_t)Bn * NC * 4 * sizeof(float));

    dim3 grid(NC, Bn);
    hipLaunchKernelGGL(k_filt, grid, dim3(TPB), 0, stream, Ig, Qg, Ag, Bg, out, PS);
    hipLaunchKernelGGL(k_post, dim3(Bn), dim3(64), 0, stream, Ag, Bg, out, PS, ROW);
    hipLaunchKernelGGL(k_norm, dim3(4096), dim3(256), 0, stream, out, ROW);
}